// Round 1
// baseline (1202.104 us; speedup 1.0000x reference)
//
#include <hip/hip_runtime.h>
#include <math.h>

#define HIDDEN 768
#define NHEADS 12
#define DHEAD  64
#define NB     8
#define LQ     512
#define LK     1024
#define LN_EPS 1e-12f

// ---------------------------------------------------------------------------
// NT GEMM: C[m][n] = alpha * sum_k A[m][k]*B[n][k]  (+bias[n]) (+res[m][n])
// Batched over blockIdx.z: g -> (bb = g/hdiv, hh = g%hdiv), offsets via strides.
// Tiles: 64x64 output per block, TK=16, 16x16 threads, 4x4 micro-tile.
// All dims assumed multiples of 64 (true for this problem), K % 16 == 0.
// ---------------------------------------------------------------------------
__global__ __launch_bounds__(256)
void gemm_nt(const float* __restrict__ A, const float* __restrict__ Bm,
             float* __restrict__ C, const float* __restrict__ bias,
             const float* __restrict__ res,
             int M, int N, int K, int lda, int ldb, int ldc,
             long sAb, long sAh, long sBb, long sBh, long sCb, long sCh,
             int hdiv, float alpha)
{
    __shared__ float As[64][17];
    __shared__ float Bs[64][17];

    int g  = blockIdx.z;
    int bb = g / hdiv, hh = g - bb * hdiv;
    A  += bb * sAb + hh * sAh;
    Bm += bb * sBb + hh * sBh;
    C  += bb * sCb + hh * sCh;

    int n0 = blockIdx.x * 64;
    int m0 = blockIdx.y * 64;
    int tx = threadIdx.x, ty = threadIdx.y;
    int t  = ty * 16 + tx;
    int lr = t >> 4;   // 0..15
    int lc = t & 15;   // 0..15

    float acc[4][4] = {};

    for (int k0 = 0; k0 < K; k0 += 16) {
#pragma unroll
        for (int i = 0; i < 4; i++) {
            As[lr + 16 * i][lc] = A[(long)(m0 + lr + 16 * i) * lda + k0 + lc];
            Bs[lr + 16 * i][lc] = Bm[(long)(n0 + lr + 16 * i) * ldb + k0 + lc];
        }
        __syncthreads();
#pragma unroll
        for (int kk = 0; kk < 16; kk++) {
            float a[4], b[4];
#pragma unroll
            for (int i = 0; i < 4; i++) a[i] = As[ty * 4 + i][kk];
#pragma unroll
            for (int j = 0; j < 4; j++) b[j] = Bs[tx * 4 + j][kk];
#pragma unroll
            for (int i = 0; i < 4; i++)
#pragma unroll
                for (int j = 0; j < 4; j++)
                    acc[i][j] += a[i] * b[j];
        }
        __syncthreads();
    }

#pragma unroll
    for (int i = 0; i < 4; i++) {
        int m = m0 + ty * 4 + i;
#pragma unroll
        for (int j = 0; j < 4; j++) {
            int n = n0 + tx * 4 + j;
            float v = alpha * acc[i][j];
            if (bias) v += bias[n];
            if (res)  v += res[(long)m * ldc + n];
            C[(long)m * ldc + n] = v;
        }
    }
}

// ---------------------------------------------------------------------------
// NN GEMM: C[m][n] = sum_k A[m][k]*B[k][n]   (batched same as above)
// ---------------------------------------------------------------------------
__global__ __launch_bounds__(256)
void gemm_nn(const float* __restrict__ A, const float* __restrict__ Bm,
             float* __restrict__ C,
             int M, int N, int K, int lda, int ldb, int ldc,
             long sAb, long sAh, long sBb, long sBh, long sCb, long sCh,
             int hdiv)
{
    __shared__ float As[64][17];
    __shared__ float Bs[16][65];

    int g  = blockIdx.z;
    int bb = g / hdiv, hh = g - bb * hdiv;
    A  += bb * sAb + hh * sAh;
    Bm += bb * sBb + hh * sBh;
    C  += bb * sCb + hh * sCh;

    int n0 = blockIdx.x * 64;
    int m0 = blockIdx.y * 64;
    int tx = threadIdx.x, ty = threadIdx.y;
    int t  = ty * 16 + tx;
    int lrA = t >> 4, lcA = t & 15;    // A tile 64x16
    int lrB = t >> 6, lcB = t & 63;    // B tile 16x64

    float acc[4][4] = {};

    for (int k0 = 0; k0 < K; k0 += 16) {
#pragma unroll
        for (int i = 0; i < 4; i++)
            As[lrA + 16 * i][lcA] = A[(long)(m0 + lrA + 16 * i) * lda + k0 + lcA];
#pragma unroll
        for (int i = 0; i < 4; i++)
            Bs[lrB + 4 * i][lcB] = Bm[(long)(k0 + lrB + 4 * i) * ldb + n0 + lcB];
        __syncthreads();
#pragma unroll
        for (int kk = 0; kk < 16; kk++) {
            float a[4], b[4];
#pragma unroll
            for (int i = 0; i < 4; i++) a[i] = As[ty * 4 + i][kk];
#pragma unroll
            for (int j = 0; j < 4; j++) b[j] = Bs[kk][tx * 4 + j];
#pragma unroll
            for (int i = 0; i < 4; i++)
#pragma unroll
                for (int j = 0; j < 4; j++)
                    acc[i][j] += a[i] * b[j];
        }
        __syncthreads();
    }

#pragma unroll
    for (int i = 0; i < 4; i++) {
        int m = m0 + ty * 4 + i;
#pragma unroll
        for (int j = 0; j < 4; j++) {
            int n = n0 + tx * 4 + j;
            C[(long)m * ldc + n] = acc[i][j];
        }
    }
}

// ---------------------------------------------------------------------------
// Softmax over rows of length LK=1024, in place; additive mask[b][k].
// One block (256 threads) per row; 4 elements (one float4) per thread.
// ---------------------------------------------------------------------------
__global__ __launch_bounds__(256)
void softmax_rows(float* __restrict__ P, const float* __restrict__ mask)
{
    long row = blockIdx.x;                 // 0 .. NB*NHEADS*LQ-1
    int  b   = (int)(row / (NHEADS * LQ));
    float*       p  = P + row * LK;
    const float* mk = mask + (long)b * LK;
    int t = threadIdx.x;

    float4 v  = ((const float4*)p)[t];
    float4 m4 = ((const float4*)mk)[t];
    v.x += m4.x; v.y += m4.y; v.z += m4.z; v.w += m4.w;

    float mx = fmaxf(fmaxf(v.x, v.y), fmaxf(v.z, v.w));
#pragma unroll
    for (int off = 32; off > 0; off >>= 1)
        mx = fmaxf(mx, __shfl_down(mx, off));

    __shared__ float smax[4], ssum[4];
    int wave = t >> 6;
    if ((t & 63) == 0) smax[wave] = mx;
    __syncthreads();
    mx = fmaxf(fmaxf(smax[0], smax[1]), fmaxf(smax[2], smax[3]));

    v.x = __expf(v.x - mx);
    v.y = __expf(v.y - mx);
    v.z = __expf(v.z - mx);
    v.w = __expf(v.w - mx);

    float s = v.x + v.y + v.z + v.w;
#pragma unroll
    for (int off = 32; off > 0; off >>= 1)
        s += __shfl_down(s, off);
    if ((t & 63) == 0) ssum[wave] = s;
    __syncthreads();
    s = ssum[0] + ssum[1] + ssum[2] + ssum[3];

    float r = 1.0f / s;
    v.x *= r; v.y *= r; v.z *= r; v.w *= r;
    ((float4*)p)[t] = v;
}

// ---------------------------------------------------------------------------
// Row LayerNorm over HIDDEN=768; one block (256 threads) per row, 3 elems each.
// ---------------------------------------------------------------------------
__global__ __launch_bounds__(256)
void layernorm_rows(const float* __restrict__ H, const float* __restrict__ gamma,
                    const float* __restrict__ beta, float* __restrict__ out)
{
    int row = blockIdx.x;                  // 0 .. NB*LQ-1
    const float* h = H + (long)row * HIDDEN;
    int t = threadIdx.x;

    float x[3];
    float s = 0.f, ss = 0.f;
#pragma unroll
    for (int i = 0; i < 3; i++) {
        x[i] = h[t + 256 * i];
        s  += x[i];
        ss += x[i] * x[i];
    }
#pragma unroll
    for (int off = 32; off > 0; off >>= 1) {
        s  += __shfl_down(s, off);
        ss += __shfl_down(ss, off);
    }
    __shared__ float sh_s[4], sh_ss[4];
    int wave = t >> 6;
    if ((t & 63) == 0) { sh_s[wave] = s; sh_ss[wave] = ss; }
    __syncthreads();
    float S  = sh_s[0] + sh_s[1] + sh_s[2] + sh_s[3];
    float SS = sh_ss[0] + sh_ss[1] + sh_ss[2] + sh_ss[3];

    float mu  = S * (1.0f / HIDDEN);
    float var = SS * (1.0f / HIDDEN) - mu * mu;
    float inv = rsqrtf(var + LN_EPS);

    float* o = out + (long)row * HIDDEN;
#pragma unroll
    for (int i = 0; i < 3; i++) {
        int c = t + 256 * i;
        o[c] = (x[i] - mu) * inv * gamma[c] + beta[c];
    }
}

// ---------------------------------------------------------------------------
extern "C" void kernel_launch(void* const* d_in, const int* in_sizes, int n_in,
                              void* d_out, int out_size, void* d_ws, size_t ws_size,
                              hipStream_t stream)
{
    const float* query = (const float*)d_in[0];   // [NB, LQ, HIDDEN]
    const float* key   = (const float*)d_in[1];   // [NB, LK, HIDDEN]
    const float* value = (const float*)d_in[2];   // [NB, LK, HIDDEN]
    const float* amask = (const float*)d_in[3];   // [NB, 1, 1, LK]
    // d_in[4] = q_attention_mask (unused by reference)
    const float* Wq    = (const float*)d_in[5];
    const float* bq    = (const float*)d_in[6];
    const float* Wk    = (const float*)d_in[7];
    const float* bk    = (const float*)d_in[8];
    const float* Wv    = (const float*)d_in[9];
    const float* bv    = (const float*)d_in[10];
    const float* Wo    = (const float*)d_in[11];
    const float* bo    = (const float*)d_in[12];
    const float* gamma = (const float*)d_in[13];
    const float* beta  = (const float*)d_in[14];

    // workspace layout (fp32): qbuf[4096x768] kbuf[8192x768] vbuf[8192x768]
    float* qbuf = (float*)d_ws;
    float* kbuf = qbuf + (long)NB * LQ * HIDDEN;
    float* vbuf = kbuf + (long)NB * LK * HIDDEN;
    float* ctxbuf = qbuf;   // reuse: qbuf dead after scores GEMM
    float* hbuf   = kbuf;   // reuse: kbuf dead after scores GEMM

    float* out0  = (float*)d_out;                       // [NB*LQ, HIDDEN]
    float* probs = out0 + (long)NB * LQ * HIDDEN;       // [NB, NHEADS, LQ, LK]

    dim3 blk(16, 16);

    // Q/K/V projections: X @ W^T + b
    gemm_nt<<<dim3(HIDDEN / 64, (NB * LQ) / 64, 1), blk, 0, stream>>>(
        query, Wq, qbuf, bq, nullptr,
        NB * LQ, HIDDEN, HIDDEN, HIDDEN, HIDDEN, HIDDEN,
        0, 0, 0, 0, 0, 0, 1, 1.0f);
    gemm_nt<<<dim3(HIDDEN / 64, (NB * LK) / 64, 1), blk, 0, stream>>>(
        key, Wk, kbuf, bk, nullptr,
        NB * LK, HIDDEN, HIDDEN, HIDDEN, HIDDEN, HIDDEN,
        0, 0, 0, 0, 0, 0, 1, 1.0f);
    gemm_nt<<<dim3(HIDDEN / 64, (NB * LK) / 64, 1), blk, 0, stream>>>(
        value, Wv, vbuf, bv, nullptr,
        NB * LK, HIDDEN, HIDDEN, HIDDEN, HIDDEN, HIDDEN,
        0, 0, 0, 0, 0, 0, 1, 1.0f);

    // scores = (Q_bh @ K_bh^T) / 8 -> probs region
    gemm_nt<<<dim3(LK / 64, LQ / 64, NB * NHEADS), blk, 0, stream>>>(
        qbuf, kbuf, probs, nullptr, nullptr,
        LQ, LK, DHEAD, HIDDEN, HIDDEN, LK,
        (long)LQ * HIDDEN, (long)DHEAD,
        (long)LK * HIDDEN, (long)DHEAD,
        (long)NHEADS * LQ * LK, (long)LQ * LK,
        NHEADS, 0.125f);

    // softmax(scores + mask) in place
    softmax_rows<<<NB * NHEADS * LQ, 256, 0, stream>>>(probs, amask);

    // ctx = P @ V_bh  -> ctxbuf laid out [NB*LQ, HIDDEN] (head h at col h*64)
    gemm_nn<<<dim3(DHEAD / 64, LQ / 64, NB * NHEADS), blk, 0, stream>>>(
        probs, vbuf, ctxbuf,
        LQ, DHEAD, LK, LK, HIDDEN, HIDDEN,
        (long)NHEADS * LQ * LK, (long)LQ * LK,
        (long)LK * HIDDEN, (long)DHEAD,
        (long)LQ * HIDDEN, (long)DHEAD,
        NHEADS);

    // h = ctx @ Wo^T + bo + query
    gemm_nt<<<dim3(HIDDEN / 64, (NB * LQ) / 64, 1), blk, 0, stream>>>(
        ctxbuf, Wo, hbuf, bo, query,
        NB * LQ, HIDDEN, HIDDEN, HIDDEN, HIDDEN, HIDDEN,
        0, 0, 0, 0, 0, 0, 1, 1.0f);

    // LayerNorm -> out
    layernorm_rows<<<NB * LQ, 256, 0, stream>>>(hbuf, gamma, beta, out0);
}

// Round 2
// 549.960 us; speedup vs baseline: 2.1858x; 2.1858x over previous
//
#include <hip/hip_runtime.h>
#include <math.h>

#define HIDDEN 768
#define NHEADS 12
#define DHEAD  64
#define NB     8
#define LQ     512
#define LK     1024
#define LN_EPS 1e-12f

typedef __attribute__((ext_vector_type(8))) short short8;
typedef __attribute__((ext_vector_type(4))) float floatx4;

// async global(16B/lane) -> LDS staging
#define GLDS16(gp, lp) __builtin_amdgcn_global_load_lds( \
    (const __attribute__((address_space(1))) void*)(gp), \
    (__attribute__((address_space(3))) void*)(lp), 16, 0, 0)

__device__ __forceinline__ short f2bf(float f) {
    unsigned u = __float_as_uint(f);
    u = u + 0x7FFFu + ((u >> 16) & 1u);   // RNE
    return (short)(u >> 16);
}

// ---------------------------------------------------------------------------
// fp32 -> bf16 elementwise convert (n4 = n/4)
// ---------------------------------------------------------------------------
__global__ __launch_bounds__(256)
void cvt_f32_bf16(const float* __restrict__ in, short* __restrict__ out, int n4)
{
    int i = blockIdx.x * 256 + threadIdx.x;
    if (i >= n4) return;
    float4 v = ((const float4*)in)[i];
    short4 o;
    o.x = f2bf(v.x); o.y = f2bf(v.y); o.z = f2bf(v.z); o.w = f2bf(v.w);
    ((short4*)out)[i] = o;
}

// ---------------------------------------------------------------------------
// bf16 NT MFMA GEMM: C[m][n] = alpha * sum_k A[m,k]*B[n,k] (+bias[n]) (+res)
// Tiles: 128x128, BK=32, 256 threads = 4 waves (2x2), wave-tile 64x64,
// frags 4x4 of mfma_f32_16x16x32_bf16. A,B staged via global_load_lds with
// XOR swizzle (chunk ^= (row>>1)&3) -> conflict-free ds_read_b128.
// M,N multiples of 128, K multiple of 32 (true for all uses here).
// Output: bf16 to Cb if Cb != null, else fp32 to Cf.
// ---------------------------------------------------------------------------
__global__ __launch_bounds__(256)
void gemm_nt_mfma(const short* __restrict__ A, const short* __restrict__ B,
                  float* __restrict__ Cf, short* __restrict__ Cb,
                  const float* __restrict__ bias, const float* __restrict__ res,
                  int K, int lda, int ldb, int ldc,
                  long sAb, long sAh, long sBb, long sBh, long sCb, long sCh,
                  int hdiv, float alpha)
{
    __shared__ short As[4096];   // 128 rows x 4 chunks x 8 bf16 (swizzled)
    __shared__ short Bs[4096];

    int g  = blockIdx.z;
    int bb = g / hdiv, hh = g - bb * hdiv;
    A += bb * sAb + hh * sAh;
    B += bb * sBb + hh * sBh;
    long coff = bb * sCb + hh * sCh;

    int n0 = blockIdx.x * 128;
    int m0 = blockIdx.y * 128;
    int t    = threadIdx.x;
    int lane = t & 63, wave = t >> 6;
    int quad = lane >> 4, l15 = lane & 15;
    int wr = wave >> 1, wc = wave & 1;

    // staging: 512 entries (row 0..127, chunk 0..3), 2 per thread
    int e0 = t, e1 = 256 + t;
    int r0 = e0 >> 2, c0 = (e0 & 3) ^ ((r0 >> 1) & 3);
    int r1 = e1 >> 2, c1 = (e1 & 3) ^ ((r1 >> 1) & 3);
    const short* Ap0 = A + (size_t)(m0 + r0) * lda + c0 * 8;
    const short* Ap1 = A + (size_t)(m0 + r1) * lda + c1 * 8;
    const short* Bp0 = B + (size_t)(n0 + r0) * ldb + c0 * 8;
    const short* Bp1 = B + (size_t)(n0 + r1) * ldb + c1 * 8;

    // fragment LDS offsets (shorts), swizzle-corrected
    int aoff[4], boff[4];
#pragma unroll
    for (int i = 0; i < 4; i++) {
        int ra = wr * 64 + i * 16 + l15;
        aoff[i] = (ra * 4 + (quad ^ ((ra >> 1) & 3))) * 8;
        int rb = wc * 64 + i * 16 + l15;
        boff[i] = (rb * 4 + (quad ^ ((rb >> 1) & 3))) * 8;
    }

    floatx4 acc[4][4] = {};

    for (int k0 = 0; k0 < K; k0 += 32) {
        GLDS16(Ap0, &As[e0 * 8]);
        GLDS16(Ap1, &As[e1 * 8]);
        GLDS16(Bp0, &Bs[e0 * 8]);
        GLDS16(Bp1, &Bs[e1 * 8]);
        Ap0 += 32; Ap1 += 32; Bp0 += 32; Bp1 += 32;
        __syncthreads();   // drains vmcnt (global_load_lds) + orders LDS

        short8 af[4], bfr[4];
#pragma unroll
        for (int i = 0; i < 4; i++) af[i]  = *(const short8*)&As[aoff[i]];
#pragma unroll
        for (int j = 0; j < 4; j++) bfr[j] = *(const short8*)&Bs[boff[j]];
#pragma unroll
        for (int i = 0; i < 4; i++)
#pragma unroll
            for (int j = 0; j < 4; j++)
                acc[i][j] = __builtin_amdgcn_mfma_f32_16x16x32_bf16(
                    af[i], bfr[j], acc[i][j], 0, 0, 0);
        __syncthreads();
    }

    // epilogue: C/D layout col=lane&15, row=quad*4+reg
    float* cf = Cf ? Cf + coff : nullptr;
    short* cb = Cb ? Cb + coff : nullptr;
#pragma unroll
    for (int i = 0; i < 4; i++) {
        int mb = m0 + wr * 64 + i * 16 + quad * 4;
#pragma unroll
        for (int j = 0; j < 4; j++) {
            int n = n0 + wc * 64 + j * 16 + l15;
            float bv = bias ? bias[n] : 0.f;
#pragma unroll
            for (int r = 0; r < 4; r++) {
                int m = mb + r;
                float v = alpha * acc[i][j][r] + bv;
                if (res) v += res[(size_t)m * ldc + n];
                if (cb) cb[(size_t)m * ldc + n] = f2bf(v);
                else    cf[(size_t)m * ldc + n] = v;
            }
        }
    }
}

// ---------------------------------------------------------------------------
// ctx = P(fp32, converted in staging) @ V(bf16)  per (batch,head).
// Tile 128(m) x 64(n), BK=32, 4 waves (2x2 over m64 x n32), frags 4x2.
// A staged via VGPR fp32->bf16 with same XOR swizzle; V-tile transposed
// through LDS into [n][k] rows (stride 40 shorts -> conflict-free b128).
// ---------------------------------------------------------------------------
__global__ __launch_bounds__(256)
void gemm_pv(const float* __restrict__ P, const short* __restrict__ V,
             short* __restrict__ C)
{
    __shared__ short As[4096];       // 128x32 swizzled
    __shared__ short Bs[64 * 40];    // V^T [n][k], row stride 40 shorts

    int g  = blockIdx.z;             // b*12 + h
    int bb = g / 12, hh = g - bb * 12;
    P += (size_t)g * (LQ * LK);
    V += (size_t)bb * (LK * HIDDEN) + hh * DHEAD;
    C += (size_t)bb * (LQ * HIDDEN) + hh * DHEAD;

    int m0 = blockIdx.y * 128;
    int t    = threadIdx.x;
    int lane = t & 63, wave = t >> 6;
    int quad = lane >> 4, l15 = lane & 15;
    int wr = wave >> 1, wc = wave & 1;

    int e0 = t, e1 = 256 + t;
    int r0 = e0 >> 2, c0 = (e0 & 3) ^ ((r0 >> 1) & 3);
    int r1 = e1 >> 2, c1 = (e1 & 3) ^ ((r1 >> 1) & 3);
    const float* Pp0 = P + (size_t)(m0 + r0) * LK + c0 * 8;
    const float* Pp1 = P + (size_t)(m0 + r1) * LK + c1 * 8;

    int bn = t & 63, kg = t >> 6;    // B staging: lane=n col, wave=k-chunk
    const short* Vp = V + (size_t)kg * 8 * HIDDEN + bn;

    int aoff[4];
#pragma unroll
    for (int i = 0; i < 4; i++) {
        int ra = wr * 64 + i * 16 + l15;
        aoff[i] = (ra * 4 + (quad ^ ((ra >> 1) & 3))) * 8;
    }
    int boff[2];
#pragma unroll
    for (int j = 0; j < 2; j++) {
        int nb = wc * 32 + j * 16 + l15;
        boff[j] = nb * 40 + quad * 8;
    }

    floatx4 acc[4][2] = {};

    for (int k0 = 0; k0 < LK; k0 += 32) {
        // A tile: fp32 -> bf16 -> LDS (swizzled)
        float4 a0 = *(const float4*)Pp0;
        float4 a1 = *(const float4*)(Pp0 + 4);
        float4 a2 = *(const float4*)Pp1;
        float4 a3 = *(const float4*)(Pp1 + 4);
        short8 s0, s1;
        s0[0]=f2bf(a0.x); s0[1]=f2bf(a0.y); s0[2]=f2bf(a0.z); s0[3]=f2bf(a0.w);
        s0[4]=f2bf(a1.x); s0[5]=f2bf(a1.y); s0[6]=f2bf(a1.z); s0[7]=f2bf(a1.w);
        s1[0]=f2bf(a2.x); s1[1]=f2bf(a2.y); s1[2]=f2bf(a2.z); s1[3]=f2bf(a2.w);
        s1[4]=f2bf(a3.x); s1[5]=f2bf(a3.y); s1[6]=f2bf(a3.z); s1[7]=f2bf(a3.w);
        *(short8*)&As[e0 * 8] = s0;
        *(short8*)&As[e1 * 8] = s1;

        // B tile: V[k0..+32][0..64] transposed to Bs[n][k]
        short8 vv;
#pragma unroll
        for (int r = 0; r < 8; r++) vv[r] = Vp[(size_t)r * HIDDEN];
        *(short8*)&Bs[bn * 40 + kg * 8] = vv;

        Pp0 += 32; Pp1 += 32; Vp += (size_t)32 * HIDDEN;
        __syncthreads();

        short8 af[4], bfr[2];
#pragma unroll
        for (int i = 0; i < 4; i++) af[i]  = *(const short8*)&As[aoff[i]];
#pragma unroll
        for (int j = 0; j < 2; j++) bfr[j] = *(const short8*)&Bs[boff[j]];
#pragma unroll
        for (int i = 0; i < 4; i++)
#pragma unroll
            for (int j = 0; j < 2; j++)
                acc[i][j] = __builtin_amdgcn_mfma_f32_16x16x32_bf16(
                    af[i], bfr[j], acc[i][j], 0, 0, 0);
        __syncthreads();
    }

#pragma unroll
    for (int i = 0; i < 4; i++) {
        int mb = m0 + wr * 64 + i * 16 + quad * 4;
#pragma unroll
        for (int j = 0; j < 2; j++) {
            int n = wc * 32 + j * 16 + l15;
#pragma unroll
            for (int r = 0; r < 4; r++)
                C[(size_t)(mb + r) * HIDDEN + n] = f2bf(acc[i][j][r]);
        }
    }
}

// ---------------------------------------------------------------------------
// Softmax over rows of length LK=1024, in place; additive mask[b][k].
// ---------------------------------------------------------------------------
__global__ __launch_bounds__(256)
void softmax_rows(float* __restrict__ P, const float* __restrict__ mask)
{
    long row = blockIdx.x;
    int  b   = (int)(row / (NHEADS * LQ));
    float*       p  = P + row * LK;
    const float* mk = mask + (long)b * LK;
    int t = threadIdx.x;

    float4 v  = ((const float4*)p)[t];
    float4 m4 = ((const float4*)mk)[t];
    v.x += m4.x; v.y += m4.y; v.z += m4.z; v.w += m4.w;

    float mx = fmaxf(fmaxf(v.x, v.y), fmaxf(v.z, v.w));
#pragma unroll
    for (int off = 32; off > 0; off >>= 1)
        mx = fmaxf(mx, __shfl_down(mx, off));

    __shared__ float smax[4], ssum[4];
    int wave = t >> 6;
    if ((t & 63) == 0) smax[wave] = mx;
    __syncthreads();
    mx = fmaxf(fmaxf(smax[0], smax[1]), fmaxf(smax[2], smax[3]));

    v.x = __expf(v.x - mx);
    v.y = __expf(v.y - mx);
    v.z = __expf(v.z - mx);
    v.w = __expf(v.w - mx);

    float s = v.x + v.y + v.z + v.w;
#pragma unroll
    for (int off = 32; off > 0; off >>= 1)
        s += __shfl_down(s, off);
    if ((t & 63) == 0) ssum[wave] = s;
    __syncthreads();
    s = ssum[0] + ssum[1] + ssum[2] + ssum[3];

    float r = 1.0f / s;
    v.x *= r; v.y *= r; v.z *= r; v.w *= r;
    ((float4*)p)[t] = v;
}

// ---------------------------------------------------------------------------
// Row LayerNorm over HIDDEN=768; one block per row.
// ---------------------------------------------------------------------------
__global__ __launch_bounds__(256)
void layernorm_rows(const float* __restrict__ H, const float* __restrict__ gamma,
                    const float* __restrict__ beta, float* __restrict__ out)
{
    int row = blockIdx.x;
    const float* h = H + (long)row * HIDDEN;
    int t = threadIdx.x;

    float x[3];
    float s = 0.f, ss = 0.f;
#pragma unroll
    for (int i = 0; i < 3; i++) {
        x[i] = h[t + 256 * i];
        s  += x[i];
        ss += x[i] * x[i];
    }
#pragma unroll
    for (int off = 32; off > 0; off >>= 1) {
        s  += __shfl_down(s, off);
        ss += __shfl_down(ss, off);
    }
    __shared__ float sh_s[4], sh_ss[4];
    int wave = t >> 6;
    if ((t & 63) == 0) { sh_s[wave] = s; sh_ss[wave] = ss; }
    __syncthreads();
    float S  = sh_s[0] + sh_s[1] + sh_s[2] + sh_s[3];
    float SS = sh_ss[0] + sh_ss[1] + sh_ss[2] + sh_ss[3];

    float mu  = S * (1.0f / HIDDEN);
    float var = SS * (1.0f / HIDDEN) - mu * mu;
    float inv = rsqrtf(var + LN_EPS);

    float* o = out + (long)row * HIDDEN;
#pragma unroll
    for (int i = 0; i < 3; i++) {
        int c = t + 256 * i;
        o[c] = (x[i] - mu) * inv * gamma[c] + beta[c];
    }
}

// ---------------------------------------------------------------------------
extern "C" void kernel_launch(void* const* d_in, const int* in_sizes, int n_in,
                              void* d_out, int out_size, void* d_ws, size_t ws_size,
                              hipStream_t stream)
{
    const float* query = (const float*)d_in[0];
    const float* key   = (const float*)d_in[1];
    const float* value = (const float*)d_in[2];
    const float* amask = (const float*)d_in[3];
    const float* Wq    = (const float*)d_in[5];
    const float* bq    = (const float*)d_in[6];
    const float* Wk    = (const float*)d_in[7];
    const float* bk    = (const float*)d_in[8];
    const float* Wv    = (const float*)d_in[9];
    const float* bv    = (const float*)d_in[10];
    const float* Wo    = (const float*)d_in[11];
    const float* bo    = (const float*)d_in[12];
    const float* gamma = (const float*)d_in[13];
    const float* beta  = (const float*)d_in[14];

    // bf16 workspace layout
    short* qx = (short*)d_ws;              // 4096*768 query bf16
    short* kx = qx + (long)4096 * 768;     // 8192*768
    short* vx = kx + (long)8192 * 768;     // 8192*768
    short* wq = vx + (long)8192 * 768;     // 768*768
    short* wk = wq + (long)768 * 768;
    short* wv = wk + (long)768 * 768;
    short* wo = wv + (long)768 * 768;
    short* qb = wo + (long)768 * 768;      // 4096*768 Q proj out
    short* kb = qb + (long)4096 * 768;     // 8192*768 K proj out
    short* vb = kb + (long)8192 * 768;     // 8192*768 V proj out
    short* ctxb = qx;                      // reuse (qx dead after Q proj)
    float* hbuf = (float*)kx;              // reuse (kx dead after K proj), 12.58 MB

    float* out0  = (float*)d_out;
    float* probs = out0 + (long)NB * LQ * HIDDEN;

    // --- convert inputs & weights to bf16 ---
    cvt_f32_bf16<<<(4096 * 768 / 4 + 255) / 256, 256, 0, stream>>>(query, qx, 4096 * 768 / 4);
    cvt_f32_bf16<<<(8192 * 768 / 4 + 255) / 256, 256, 0, stream>>>(key,   kx, 8192 * 768 / 4);
    cvt_f32_bf16<<<(8192 * 768 / 4 + 255) / 256, 256, 0, stream>>>(value, vx, 8192 * 768 / 4);
    cvt_f32_bf16<<<(768 * 768 / 4 + 255) / 256, 256, 0, stream>>>(Wq, wq, 768 * 768 / 4);
    cvt_f32_bf16<<<(768 * 768 / 4 + 255) / 256, 256, 0, stream>>>(Wk, wk, 768 * 768 / 4);
    cvt_f32_bf16<<<(768 * 768 / 4 + 255) / 256, 256, 0, stream>>>(Wv, wv, 768 * 768 / 4);
    cvt_f32_bf16<<<(768 * 768 / 4 + 255) / 256, 256, 0, stream>>>(Wo, wo, 768 * 768 / 4);

    // --- QKV projections (bf16 out) ---
    gemm_nt_mfma<<<dim3(6, 32, 1), 256, 0, stream>>>(
        qx, wq, nullptr, qb, bq, nullptr, HIDDEN, HIDDEN, HIDDEN, HIDDEN,
        0, 0, 0, 0, 0, 0, 1, 1.0f);
    gemm_nt_mfma<<<dim3(6, 64, 1), 256, 0, stream>>>(
        kx, wk, nullptr, kb, bk, nullptr, HIDDEN, HIDDEN, HIDDEN, HIDDEN,
        0, 0, 0, 0, 0, 0, 1, 1.0f);
    gemm_nt_mfma<<<dim3(6, 64, 1), 256, 0, stream>>>(
        vx, wv, nullptr, vb, bv, nullptr, HIDDEN, HIDDEN, HIDDEN, HIDDEN,
        0, 0, 0, 0, 0, 0, 1, 1.0f);

    // --- scores = (Q K^T)/8 -> probs fp32 ---
    gemm_nt_mfma<<<dim3(8, 4, 96), 256, 0, stream>>>(
        qb, kb, probs, nullptr, nullptr, nullptr, DHEAD, HIDDEN, HIDDEN, LK,
        (long)LQ * HIDDEN, (long)DHEAD,
        (long)LK * HIDDEN, (long)DHEAD,
        (long)NHEADS * LQ * LK, (long)LQ * LK,
        NHEADS, 0.125f);

    // --- softmax in place ---
    softmax_rows<<<NB * NHEADS * LQ, 256, 0, stream>>>(probs, amask);

    // --- ctx = P V (bf16 out) ---
    gemm_pv<<<dim3(1, 4, 96), 256, 0, stream>>>(probs, vb, ctxb);

    // --- h = ctx Wo^T + bo + query (fp32) ---
    gemm_nt_mfma<<<dim3(6, 32, 1), 256, 0, stream>>>(
        ctxb, wo, hbuf, nullptr, bo, query, HIDDEN, HIDDEN, HIDDEN, HIDDEN,
        0, 0, 0, 0, 0, 0, 1, 1.0f);

    // --- LayerNorm ---
    layernorm_rows<<<NB * LQ, 256, 0, stream>>>(hbuf, gamma, beta, out0);
}

// Round 3
// 548.485 us; speedup vs baseline: 2.1917x; 1.0027x over previous
//
#include <hip/hip_runtime.h>
#include <math.h>

#define HIDDEN 768
#define NHEADS 12
#define DHEAD  64
#define NB     8
#define LQ     512
#define LK     1024
#define LN_EPS 1e-12f
#define STRIDE_S 1028   // fp32 per S row (1024+4 pad): lane-stride ≡ 4 mod 32

typedef __attribute__((ext_vector_type(8))) short short8;
typedef __attribute__((ext_vector_type(4))) float floatx4;

#define GLDS16(gp, lp) __builtin_amdgcn_global_load_lds( \
    (const __attribute__((address_space(1))) void*)(gp), \
    (__attribute__((address_space(3))) void*)(lp), 16, 0, 0)

__device__ __forceinline__ short f2bf(float f) {
    unsigned u = __float_as_uint(f);
    u = u + 0x7FFFu + ((u >> 16) & 1u);   // RNE
    return (short)(u >> 16);
}

// ---------------------------------------------------------------------------
// fp32 -> bf16 elementwise convert (n4 = n/4)
// ---------------------------------------------------------------------------
__global__ __launch_bounds__(256)
void cvt_f32_bf16(const float* __restrict__ in, short* __restrict__ out, int n4)
{
    int i = blockIdx.x * 256 + threadIdx.x;
    if (i >= n4) return;
    float4 v = ((const float4*)in)[i];
    short4 o;
    o.x = f2bf(v.x); o.y = f2bf(v.y); o.z = f2bf(v.z); o.w = f2bf(v.w);
    ((short4*)out)[i] = o;
}

// ---------------------------------------------------------------------------
// bf16 NT MFMA GEMM (128x128 tile, BK=32) - unchanged from round 2.
// ---------------------------------------------------------------------------
__global__ __launch_bounds__(256)
void gemm_nt_mfma(const short* __restrict__ A, const short* __restrict__ B,
                  float* __restrict__ Cf, short* __restrict__ Cb,
                  const float* __restrict__ bias, const float* __restrict__ res,
                  int K, int lda, int ldb, int ldc, float alpha)
{
    __shared__ short As[4096];
    __shared__ short Bs[4096];

    int n0 = blockIdx.x * 128;
    int m0 = blockIdx.y * 128;
    int t    = threadIdx.x;
    int lane = t & 63, wave = t >> 6;
    int quad = lane >> 4, l15 = lane & 15;
    int wr = wave >> 1, wc = wave & 1;

    int e0 = t, e1 = 256 + t;
    int r0 = e0 >> 2, c0 = (e0 & 3) ^ ((r0 >> 1) & 3);
    int r1 = e1 >> 2, c1 = (e1 & 3) ^ ((r1 >> 1) & 3);
    const short* Ap0 = A + (size_t)(m0 + r0) * lda + c0 * 8;
    const short* Ap1 = A + (size_t)(m0 + r1) * lda + c1 * 8;
    const short* Bp0 = B + (size_t)(n0 + r0) * ldb + c0 * 8;
    const short* Bp1 = B + (size_t)(n0 + r1) * ldb + c1 * 8;

    int aoff[4], boff[4];
#pragma unroll
    for (int i = 0; i < 4; i++) {
        int ra = wr * 64 + i * 16 + l15;
        aoff[i] = (ra * 4 + (quad ^ ((ra >> 1) & 3))) * 8;
        int rb = wc * 64 + i * 16 + l15;
        boff[i] = (rb * 4 + (quad ^ ((rb >> 1) & 3))) * 8;
    }

    floatx4 acc[4][4] = {};

    for (int k0 = 0; k0 < K; k0 += 32) {
        GLDS16(Ap0, &As[e0 * 8]);
        GLDS16(Ap1, &As[e1 * 8]);
        GLDS16(Bp0, &Bs[e0 * 8]);
        GLDS16(Bp1, &Bs[e1 * 8]);
        Ap0 += 32; Ap1 += 32; Bp0 += 32; Bp1 += 32;
        __syncthreads();

        short8 af[4], bfr[4];
#pragma unroll
        for (int i = 0; i < 4; i++) af[i]  = *(const short8*)&As[aoff[i]];
#pragma unroll
        for (int j = 0; j < 4; j++) bfr[j] = *(const short8*)&Bs[boff[j]];
#pragma unroll
        for (int i = 0; i < 4; i++)
#pragma unroll
            for (int j = 0; j < 4; j++)
                acc[i][j] = __builtin_amdgcn_mfma_f32_16x16x32_bf16(
                    af[i], bfr[j], acc[i][j], 0, 0, 0);
        __syncthreads();
    }

#pragma unroll
    for (int i = 0; i < 4; i++) {
        int mb = m0 + wr * 64 + i * 16 + quad * 4;
#pragma unroll
        for (int j = 0; j < 4; j++) {
            int n = n0 + wc * 64 + j * 16 + l15;
            float bv = bias ? bias[n] : 0.f;
#pragma unroll
            for (int r = 0; r < 4; r++) {
                int m = mb + r;
                float v = alpha * acc[i][j][r] + bv;
                if (res) v += res[(size_t)m * ldc + n];
                if (Cb) Cb[(size_t)m * ldc + n] = f2bf(v);
                else    Cf[(size_t)m * ldc + n] = v;
            }
        }
    }
}

// ---------------------------------------------------------------------------
// Transpose V proj: vb [B, LK, 768] -> vt [bh][64 d][1024 k]
// ---------------------------------------------------------------------------
__global__ __launch_bounds__(256)
void transpose_v(const short* __restrict__ vb, short* __restrict__ vt)
{
    __shared__ short T[256 * 72];   // 36 KB, pad 72 to break bank conflicts
    int kt = blockIdx.x, bh = blockIdx.y;
    int b = bh / 12, h = bh - b * 12;
    int t = threadIdx.x;
    const short* src = vb + ((size_t)b * LK + kt * 256) * HIDDEN + h * DHEAD;
#pragma unroll
    for (int it = 0; it < 8; it++) {
        int s = it * 256 + t;
        int k = s >> 3, c = s & 7;
        *(short8*)&T[k * 72 + c * 8] =
            *(const short8*)&src[(size_t)k * HIDDEN + c * 8];
    }
    __syncthreads();
    short* dst = vt + (size_t)bh * DHEAD * LK + kt * 256;
#pragma unroll
    for (int it = 0; it < 8; it++) {
        int s = it * 256 + t;
        int d = s >> 5, kc = s & 31;
        short8 v;
#pragma unroll
        for (int i = 0; i < 8; i++) v[i] = T[(kc * 8 + i) * 72 + d];
        *(short8*)&dst[(size_t)d * LK + kc * 8] = v;
    }
}

// ---------------------------------------------------------------------------
// Fused attention: per (b,h,32-row Q tile): S=QK^T/8+mask -> softmax
// -> probs (single write) -> ctx = P@V (rescaled by 1/l at epilogue).
// S resident in LDS fp32 (stride 1028). K/V chunks staged via GLDS+swizzle.
// ---------------------------------------------------------------------------
__global__ __launch_bounds__(256)
void fused_attn(const short* __restrict__ qb, const short* __restrict__ kb,
                const short* __restrict__ vt, const float* __restrict__ amask,
                float* __restrict__ probs, short* __restrict__ ctxb)
{
    __shared__ float S[32 * STRIDE_S];     // 128.5 KB
    __shared__ short KV[8192];             // 16 KB staging (K or V chunk)
    __shared__ short Qs[2048];             // 4 KB
    __shared__ float maskL[1024];          // 4 KB
    __shared__ float mpart[4][32];
    __shared__ float mrow[32], lrow[32];

    int qt = blockIdx.x;                   // 0..15
    int bh = blockIdx.y;                   // 0..95
    int b  = bh / 12, h = bh - b * 12;
    int m0 = qt * 32;

    const short* Qg = qb + ((size_t)b * LQ + m0) * HIDDEN + h * DHEAD;
    const short* Kg = kb + (size_t)b * LK * HIDDEN + h * DHEAD;
    const short* Vg = vt + (size_t)bh * DHEAD * LK;
    const float* Mg = amask + (size_t)b * LK;
    float* Pg = probs + (size_t)bh * LQ * LK + (size_t)m0 * LK;
    short* Cg = ctxb + ((size_t)b * LQ + m0) * HIDDEN + h * DHEAD;

    int t = threadIdx.x;
    int lane = t & 63, w = t >> 6;
    int quad = lane >> 4, l15 = lane & 15;

    // stage Q tile (32x64, swizzled), mask, K chunk 0
    {
        int r = t >> 3, cs = t & 7, c = cs ^ (r & 7);
        GLDS16(Qg + (size_t)r * HIDDEN + c * 8, &Qs[t * 8]);
    }
    ((float4*)maskL)[t] = ((const float4*)Mg)[t];
#pragma unroll
    for (int I = 0; I < 4; I++) {
        int s = I * 256 + t;
        int r = s >> 3, cs = s & 7, c = cs ^ (r & 7);
        GLDS16(Kg + (size_t)r * HIDDEN + c * 8, &KV[s * 8]);
    }
    __syncthreads();

    // Q fragments: A[m=l15][k=quad*8+j], held for the whole scores phase
    short8 af[2][2];
#pragma unroll
    for (int i = 0; i < 2; i++)
#pragma unroll
        for (int ks = 0; ks < 2; ks++) {
            int row = i * 16 + l15;
            int cs = (ks * 4 + quad) ^ (row & 7);
            af[i][ks] = *(const short8*)&Qs[(row * 8 + cs) * 8];
        }

    float mx[8];
#pragma unroll
    for (int i = 0; i < 8; i++) mx[i] = -3.0e38f;

    // ================= scores phase (8 chunks of 128 K-rows) ==============
    for (int kc = 0; kc < 8; kc++) {
        floatx4 acc[2][2] = {};   // [mfrag][nfrag]; wave w owns cols w*32..+32
#pragma unroll
        for (int ks = 0; ks < 2; ks++)
#pragma unroll
            for (int j = 0; j < 2; j++) {
                int rK = w * 32 + j * 16 + l15;
                int cs = (ks * 4 + quad) ^ (rK & 7);
                short8 bf = *(const short8*)&KV[(rK * 8 + cs) * 8];
#pragma unroll
                for (int i = 0; i < 2; i++)
                    acc[i][j] = __builtin_amdgcn_mfma_f32_16x16x32_bf16(
                        af[i][ks], bf, acc[i][j], 0, 0, 0);
            }
        __syncthreads();                   // all KV reads done
        if (kc < 7) {                      // async-stage next K chunk
            const short* Kn = Kg + (size_t)(kc + 1) * 128 * HIDDEN;
#pragma unroll
            for (int I = 0; I < 4; I++) {
                int s = I * 256 + t;
                int r = s >> 3, cs = s & 7, c = cs ^ (r & 7);
                GLDS16(Kn + (size_t)r * HIDDEN + c * 8, &KV[s * 8]);
            }
        }
        // epilogue overlaps staging: scale+mask -> S LDS, track row max
#pragma unroll
        for (int i = 0; i < 2; i++)
#pragma unroll
            for (int j = 0; j < 2; j++) {
                int n = kc * 128 + w * 32 + j * 16 + l15;
                float mk = maskL[n];
#pragma unroll
                for (int r = 0; r < 4; r++) {
                    int m = i * 16 + quad * 4 + r;
                    float v = acc[i][j][r] * 0.125f + mk;
                    S[m * STRIDE_S + n] = v;
                    mx[i * 4 + r] = fmaxf(mx[i * 4 + r], v);
                }
            }
        __syncthreads();
    }

    // row max: shuffle across l15, LDS across waves
#pragma unroll
    for (int d = 1; d < 16; d <<= 1)
#pragma unroll
        for (int i = 0; i < 8; i++)
            mx[i] = fmaxf(mx[i], __shfl_xor(mx[i], d));
    if (l15 == 0)
#pragma unroll
        for (int i = 0; i < 2; i++)
#pragma unroll
            for (int r = 0; r < 4; r++)
                mpart[w][i * 16 + quad * 4 + r] = mx[i * 4 + r];
    __syncthreads();
    if (t < 32)
        mrow[t] = fmaxf(fmaxf(mpart[0][t], mpart[1][t]),
                        fmaxf(mpart[2][t], mpart[3][t]));
    // stage V chunk 0 while softmax runs
#pragma unroll
    for (int I = 0; I < 4; I++) {
        int s = I * 256 + t;
        int n = s >> 4, cs = s & 15, c = cs ^ (n & 15);
        GLDS16(Vg + (size_t)n * LK + c * 8, &KV[s * 8]);
    }
    __syncthreads();

    // exp in place (unnormalized) + row sums
    {
        int r = t >> 3, seg = t & 7;
        float mr = mrow[r];
        float sum = 0.f;
        float4* Srow = (float4*)&S[r * STRIDE_S + seg * 128];
#pragma unroll
        for (int i = 0; i < 32; i++) {
            float4 v = Srow[i];
            v.x = __expf(v.x - mr); v.y = __expf(v.y - mr);
            v.z = __expf(v.z - mr); v.w = __expf(v.w - mr);
            Srow[i] = v;
            sum += v.x + v.y + v.z + v.w;
        }
#pragma unroll
        for (int d = 1; d < 8; d <<= 1) sum += __shfl_xor(sum, d);
        if (seg == 0) lrow[r] = sum;
    }
    __syncthreads();

    // probs: single normalized coalesced write
    for (int it = 0; it < 32; it++) {
        int idx = it * 256 + t;
        int r = idx >> 8, c4 = idx & 255;
        float inv = 1.0f / lrow[r];
        float4 v = *(const float4*)&S[r * STRIDE_S + c4 * 4];
        v.x *= inv; v.y *= inv; v.z *= inv; v.w *= inv;
        ((float4*)(Pg + (size_t)r * LK))[c4] = v;
    }

    // ================= PV phase =================
    int wr = w >> 1, wc = w & 1;           // wave: m-half x n-half
    floatx4 accO[2] = {};

    for (int kc = 0; kc < 8; kc++) {
        short8 pa[4];
#pragma unroll
        for (int ks = 0; ks < 4; ks++) {   // A-frag: S fp32 -> bf16
            const float* sp =
                &S[(wr * 16 + l15) * STRIDE_S + kc * 128 + ks * 32 + quad * 8];
            float4 v0 = *(const float4*)sp;
            float4 v1 = *(const float4*)(sp + 4);
            short8 s8;
            s8[0]=f2bf(v0.x); s8[1]=f2bf(v0.y); s8[2]=f2bf(v0.z); s8[3]=f2bf(v0.w);
            s8[4]=f2bf(v1.x); s8[5]=f2bf(v1.y); s8[6]=f2bf(v1.z); s8[7]=f2bf(v1.w);
            pa[ks] = s8;
        }
#pragma unroll
        for (int ks = 0; ks < 4; ks++)
#pragma unroll
            for (int j = 0; j < 2; j++) {
                int n = wc * 32 + j * 16 + l15;
                int cs = (ks * 4 + quad) ^ (n & 15);
                short8 bf = *(const short8*)&KV[(n * 16 + cs) * 8];
                accO[j] = __builtin_amdgcn_mfma_f32_16x16x32_bf16(
                    pa[ks], bf, accO[j], 0, 0, 0);
            }
        __syncthreads();
        if (kc < 7) {
            const short* Vn = Vg + (kc + 1) * 128;
#pragma unroll
            for (int I = 0; I < 4; I++) {
                int s = I * 256 + t;
                int n = s >> 4, cs = s & 15, c = cs ^ (n & 15);
                GLDS16(Vn + (size_t)n * LK + c * 8, &KV[s * 8]);
            }
        }
        __syncthreads();
    }

    // ctx epilogue: rescale by 1/l, bf16 out
    float inv[4];
#pragma unroll
    for (int r = 0; r < 4; r++) inv[r] = 1.0f / lrow[wr * 16 + quad * 4 + r];
#pragma unroll
    for (int j = 0; j < 2; j++) {
        int n = wc * 32 + j * 16 + l15;
#pragma unroll
        for (int r = 0; r < 4; r++) {
            int m = wr * 16 + quad * 4 + r;
            Cg[(size_t)m * HIDDEN + n] = f2bf(accO[j][r] * inv[r]);
        }
    }
}

// ---------------------------------------------------------------------------
// Row LayerNorm over HIDDEN=768; one block per row.
// ---------------------------------------------------------------------------
__global__ __launch_bounds__(256)
void layernorm_rows(const float* __restrict__ H, const float* __restrict__ gamma,
                    const float* __restrict__ beta, float* __restrict__ out)
{
    int row = blockIdx.x;
    const float* h = H + (long)row * HIDDEN;
    int t = threadIdx.x;

    float x[3];
    float s = 0.f, ss = 0.f;
#pragma unroll
    for (int i = 0; i < 3; i++) {
        x[i] = h[t + 256 * i];
        s  += x[i];
        ss += x[i] * x[i];
    }
#pragma unroll
    for (int off = 32; off > 0; off >>= 1) {
        s  += __shfl_down(s, off);
        ss += __shfl_down(ss, off);
    }
    __shared__ float sh_s[4], sh_ss[4];
    int wave = t >> 6;
    if ((t & 63) == 0) { sh_s[wave] = s; sh_ss[wave] = ss; }
    __syncthreads();
    float S  = sh_s[0] + sh_s[1] + sh_s[2] + sh_s[3];
    float SS = sh_ss[0] + sh_ss[1] + sh_ss[2] + sh_ss[3];

    float mu  = S * (1.0f / HIDDEN);
    float var = SS * (1.0f / HIDDEN) - mu * mu;
    float inv = rsqrtf(var + LN_EPS);

    float* o = out + (long)row * HIDDEN;
#pragma unroll
    for (int i = 0; i < 3; i++) {
        int c = t + 256 * i;
        o[c] = (x[i] - mu) * inv * gamma[c] + beta[c];
    }
}

// ---------------------------------------------------------------------------
extern "C" void kernel_launch(void* const* d_in, const int* in_sizes, int n_in,
                              void* d_out, int out_size, void* d_ws, size_t ws_size,
                              hipStream_t stream)
{
    const float* query = (const float*)d_in[0];
    const float* key   = (const float*)d_in[1];
    const float* value = (const float*)d_in[2];
    const float* amask = (const float*)d_in[3];
    const float* Wq    = (const float*)d_in[5];
    const float* bq    = (const float*)d_in[6];
    const float* Wk    = (const float*)d_in[7];
    const float* bk    = (const float*)d_in[8];
    const float* Wv    = (const float*)d_in[9];
    const float* bv    = (const float*)d_in[10];
    const float* Wo    = (const float*)d_in[11];
    const float* bo    = (const float*)d_in[12];
    const float* gamma = (const float*)d_in[13];
    const float* beta  = (const float*)d_in[14];

    // bf16 workspace layout (same footprint as round 2: ~67.7 MB)
    short* qx = (short*)d_ws;              // 4096*768  query bf16
    short* kx = qx + (long)4096 * 768;     // 8192*768  key bf16
    short* vx = kx + (long)8192 * 768;     // 8192*768  value bf16
    short* wq = vx + (long)8192 * 768;     // 768*768 x4 weights
    short* wk = wq + (long)768 * 768;
    short* wv = wk + (long)768 * 768;
    short* wo = wv + (long)768 * 768;
    short* qb = wo + (long)768 * 768;      // 4096*768  Q proj
    short* kb = qb + (long)4096 * 768;     // 8192*768  K proj
    short* vb = kb + (long)8192 * 768;     // 8192*768  V proj
    short* ctxb = qx;                      // reuse: qx dead after Q proj
    short* vt   = kx;                      // reuse: kx dead after K proj
    float* hbuf = (float*)vx;              // reuse: vx dead after V proj

    float* out0  = (float*)d_out;
    float* probs = out0 + (long)NB * LQ * HIDDEN;

    cvt_f32_bf16<<<(4096 * 768 / 4 + 255) / 256, 256, 0, stream>>>(query, qx, 4096 * 768 / 4);
    cvt_f32_bf16<<<(8192 * 768 / 4 + 255) / 256, 256, 0, stream>>>(key,   kx, 8192 * 768 / 4);
    cvt_f32_bf16<<<(8192 * 768 / 4 + 255) / 256, 256, 0, stream>>>(value, vx, 8192 * 768 / 4);
    cvt_f32_bf16<<<(768 * 768 / 4 + 255) / 256, 256, 0, stream>>>(Wq, wq, 768 * 768 / 4);
    cvt_f32_bf16<<<(768 * 768 / 4 + 255) / 256, 256, 0, stream>>>(Wk, wk, 768 * 768 / 4);
    cvt_f32_bf16<<<(768 * 768 / 4 + 255) / 256, 256, 0, stream>>>(Wv, wv, 768 * 768 / 4);
    cvt_f32_bf16<<<(768 * 768 / 4 + 255) / 256, 256, 0, stream>>>(Wo, wo, 768 * 768 / 4);

    // QKV projections (bf16 out)
    gemm_nt_mfma<<<dim3(6, 32), 256, 0, stream>>>(
        qx, wq, nullptr, qb, bq, nullptr, HIDDEN, HIDDEN, HIDDEN, HIDDEN, 1.0f);
    gemm_nt_mfma<<<dim3(6, 64), 256, 0, stream>>>(
        kx, wk, nullptr, kb, bk, nullptr, HIDDEN, HIDDEN, HIDDEN, HIDDEN, 1.0f);
    gemm_nt_mfma<<<dim3(6, 64), 256, 0, stream>>>(
        vx, wv, nullptr, vb, bv, nullptr, HIDDEN, HIDDEN, HIDDEN, HIDDEN, 1.0f);

    // V -> [bh][d][k] for GLDS-friendly PV staging
    transpose_v<<<dim3(4, 96), 256, 0, stream>>>(vb, vt);

    // fused attention: scores+softmax+probs+PV
    fused_attn<<<dim3(16, 96), 256, 0, stream>>>(qb, kb, vt, amask, probs, ctxb);

    // h = ctx @ Wo^T + bo + query (fp32)
    gemm_nt_mfma<<<dim3(6, 32), 256, 0, stream>>>(
        ctxb, wo, hbuf, nullptr, bo, query, HIDDEN, HIDDEN, HIDDEN, HIDDEN, 1.0f);

    layernorm_rows<<<NB * LQ, 256, 0, stream>>>(hbuf, gamma, beta, out0);
}